// Round 1
// 971.954 us; speedup vs baseline: 1.0101x; 1.0101x over previous
//
#include <hip/hip_runtime.h>
#include <cstdint>
#include <cstddef>

#define BATCH 16
#define CIN   1024
#define CH    512
#define HW    4096

static constexpr float LN_EPS = 1e-5f;

typedef __bf16 bf16x8 __attribute__((ext_vector_type(8)));
typedef float  f32x4  __attribute__((ext_vector_type(4)));

__device__ __forceinline__ float sigmoidf_(float v) { return 1.0f / (1.0f + __expf(-v)); }

// fp32 -> bf16 bits, round-to-nearest-even
__device__ __forceinline__ unsigned short f2bf(float f) {
    union { float f; uint32_t u; } c; c.f = f;
    uint32_t r = (c.u + 0x7fffu + ((c.u >> 16) & 1u)) >> 16;
    return (unsigned short)r;
}

#define GLOAD_LDS16(g, l)                                                  \
    __builtin_amdgcn_global_load_lds(                                      \
        (const __attribute__((address_space(1))) void*)(g),                \
        (__attribute__((address_space(3))) void*)(l), 16, 0, 0)

// ---------------------------------------------------------------------------
// x[b,c,n] fp32 -> xt[b,n,c] bf16  (transpose so k=c is contiguous for MFMA)
// FUSED: partial dot with w_qr (fp32) -> atomicAdd into maskpre[b,n].
// This removes the phase-0 mt=4 GEMM tile (128x4096 computed for 1 row).
// ---------------------------------------------------------------------------
__global__ __launch_bounds__(256) void transpose_convert(
    const float* __restrict__ x, const float* __restrict__ wqr,
    unsigned short* __restrict__ xt, float* __restrict__ maskpre)
{
    const int b  = blockIdx.z;
    const int c0 = blockIdx.y * 64;
    const int n0 = blockIdx.x * 64;
    __shared__ float t[64][65];
    const int tid = threadIdx.x;
    const int tx = tid & 15, ty = tid >> 4;
    const float* xb = x + ((size_t)b * CIN + c0) * HW + n0;
#pragma unroll
    for (int rr = 0; rr < 4; ++rr) {
        const int row = ty + rr * 16;
        float4 v = *(const float4*)(xb + (size_t)row * HW + tx * 4);
        t[row][tx * 4 + 0] = v.x; t[row][tx * 4 + 1] = v.y;
        t[row][tx * 4 + 2] = v.z; t[row][tx * 4 + 3] = v.w;
    }
    __syncthreads();
    const int n  = tid >> 2;
    const int cp = (tid & 3) * 16;
    __align__(16) unsigned short tmp[16];
    float part = 0.f;
#pragma unroll
    for (int i = 0; i < 16; ++i) {
        const float v = t[cp + i][n];
        tmp[i] = f2bf(v);
        part = fmaf(wqr[c0 + cp + i], v, part);   // w_qr dot (pre-relu, fp32)
    }
    unsigned short* dst = xt + ((size_t)b * HW + n0 + n) * CIN + c0 + cp;
    ((uint4*)dst)[0] = ((const uint4*)tmp)[0];
    ((uint4*)dst)[1] = ((const uint4*)tmp)[1];
    // reduce 4 threads (tid&3) covering column n, one atomic per n per block
    part += __shfl_xor(part, 1);
    part += __shfl_xor(part, 2);
    if ((tid & 3) == 0) atomicAdd(&maskpre[(size_t)b * HW + n0 + n], part);
}

// ---------------------------------------------------------------------------
// weight convert: wA (512 rows: w_ql), wB (1024 rows: w_vr[512] + w_vl[512])
// ---------------------------------------------------------------------------
__global__ __launch_bounds__(256) void wconvert(
    const float* __restrict__ wvr, const float* __restrict__ wql,
    const float* __restrict__ wvl,
    unsigned short* __restrict__ wA, unsigned short* __restrict__ wB)
{
    const int idx = blockIdx.x * 256 + threadIdx.x;
    if (idx < 512 * 1024) {
        wA[idx] = f2bf(wql[idx]);
    } else {
        const int j = idx - 512 * 1024;
        const int row = j >> 10, col = j & 1023;
        const float v = (row < 512) ? wvr[row * 1024 + col] : wvl[(row - 512) * 1024 + col];
        wB[j] = f2bf(v);
    }
}

// ---------------------------------------------------------------------------
// MFMA bf16 GEMM, 128x128 tile, BK=32, 16x16x32 mfma, 4 waves (2x2 of 64x64).
// 3-deep software pipeline: 3 LDS buffers, counted s_waitcnt vmcnt(4) BEFORE
// a raw s_barrier (so all waves' stage(t) writes are visible), prefetch t+2,
// then ds_read+MFMA on tile t. One barrier per K-step; vmcnt never drains to
// 0 in steady state (T3+T4). NO __syncthreads() in the loop (it would emit
// vmcnt(0) and re-serialize the pipeline).
// phase 0: gmean[b,o] += sum_n relu            (grid y = 4, w_ql only)
// phase 1: mt 0-3 -> ctx += relu*mask (sum_n); mt 4-7 -> cattnp += relu*avgx
// ---------------------------------------------------------------------------
__global__ __launch_bounds__(256) void mfma_gemm(
    const unsigned short* __restrict__ xt,   // [b][n][c] bf16
    const unsigned short* __restrict__ wst,  // stacked weights bf16 [o][c]
    const int phase,
    const float* __restrict__ maskp,         // phase 1 in
    const float* __restrict__ avgx,          // phase 1 in
    float* __restrict__ gmean,               // phase 0 out
    float* __restrict__ ctx,                 // phase 1 out
    float* __restrict__ cattnp)              // phase 1 out
{
    const int b  = blockIdx.z;
    const int mt = blockIdx.y;
    const int n0 = blockIdx.x * 128;
    const int o0 = mt * 128;

    const int tid  = threadIdx.x;
    const int w    = tid >> 6;
    const int lane = tid & 63;
    const int wm = (w >> 1) * 64;
    const int wn = (w & 1) * 64;

    // 3 buffers x 8KB per matrix = 48 KB total LDS -> 3 blocks/CU
    __shared__ __align__(16) unsigned short As[3 * 4096];
    __shared__ __align__(16) unsigned short Bs[3 * 4096];

    f32x4 acc[4][4];
#pragma unroll
    for (int mi = 0; mi < 4; ++mi)
#pragma unroll
        for (int nj = 0; nj < 4; ++nj) acc[mi][nj] = (f32x4){0.f, 0.f, 0.f, 0.f};

    // staging: 512 chunks per matrix; wave w instr s covers chunks [(w*2+s)*64, +64)
    const int ch0 = (w * 2 + 0) * 64 + lane;
    const int ch1 = (w * 2 + 1) * 64 + lane;
    const int qA0 = ch0 >> 7, rA0 = ch0 & 127;
    const int qA1 = ch1 >> 7, rA1 = ch1 & 127;
    const unsigned short* gA0 = wst + (size_t)(o0 + rA0) * CIN + qA0 * 8;
    const unsigned short* gA1 = wst + (size_t)(o0 + rA1) * CIN + qA1 * 8;
    const unsigned short* gB0 = xt + ((size_t)b * HW + n0 + rA0) * CIN + qA0 * 8;
    const unsigned short* gB1 = xt + ((size_t)b * HW + n0 + rA1) * CIN + qA1 * 8;
    const int la0 = (w * 2 + 0) * 512;   // shorts offset of this wave's chunk block
    const int la1 = (w * 2 + 1) * 512;

    const int qr = (lane >> 4) * 128;
    const int lr = lane & 15;

#define STAGE(tt, slot) do {                                               \
        const int cc_ = (tt) * 32;                                         \
        unsigned short* a_ = As + (slot) * 4096;                           \
        unsigned short* b_ = Bs + (slot) * 4096;                           \
        GLOAD_LDS16(gA0 + cc_, a_ + la0);                                  \
        GLOAD_LDS16(gA1 + cc_, a_ + la1);                                  \
        GLOAD_LDS16(gB0 + cc_, b_ + la0);                                  \
        GLOAD_LDS16(gB1 + cc_, b_ + la1);                                  \
    } while (0)

    STAGE(0, 0);
    STAGE(1, 1);

    int cur = 0;
    for (int t = 0; t < 32; ++t) {
        // wait for MY stage(t) (oldest 4 of <=8 outstanding), then barrier:
        // after the barrier ALL waves' stage(t) writes are visible, and all
        // waves are done reading the buffer stage(t+2) will overwrite.
        if (t < 31) asm volatile("s_waitcnt vmcnt(4)\n\ts_barrier" ::: "memory");
        else        asm volatile("s_waitcnt vmcnt(0)\n\ts_barrier" ::: "memory");
        if (t + 2 < 32) {
            int slot = cur + 2; if (slot >= 3) slot -= 3;
            STAGE(t + 2, slot);
        }
        const unsigned short* Ab = As + cur * 4096;
        const unsigned short* Bb = Bs + cur * 4096;
        bf16x8 af[4], bfr[4];
#pragma unroll
        for (int mi = 0; mi < 4; ++mi)
            af[mi] = *(const bf16x8*)(Ab + (size_t)(qr + wm + mi * 16 + lr) * 8);
#pragma unroll
        for (int nj = 0; nj < 4; ++nj)
            bfr[nj] = *(const bf16x8*)(Bb + (size_t)(qr + wn + nj * 16 + lr) * 8);
        __builtin_amdgcn_s_setprio(1);
#pragma unroll
        for (int mi = 0; mi < 4; ++mi)
#pragma unroll
            for (int nj = 0; nj < 4; ++nj)
                acc[mi][nj] = __builtin_amdgcn_mfma_f32_16x16x32_bf16(
                    af[mi], bfr[nj], acc[mi][nj], 0, 0, 0);
        __builtin_amdgcn_s_setprio(0);
        cur = (cur == 2) ? 0 : cur + 1;
    }
#undef STAGE

    // ---- epilogues (C/D layout: col = lane&15, row = (lane>>4)*4 + reg) ----
    const int quad = lane >> 4;
    if (phase == 0) {
        // gmean[b][o] += sum_n relu
#pragma unroll
        for (int mi = 0; mi < 4; ++mi)
#pragma unroll
            for (int r = 0; r < 4; ++r) {
                float v = 0.f;
#pragma unroll
                for (int nj = 0; nj < 4; ++nj) v += fmaxf(acc[mi][nj][r], 0.f);
                v += __shfl_xor(v, 1); v += __shfl_xor(v, 2);
                v += __shfl_xor(v, 4); v += __shfl_xor(v, 8);
                if (lr == 0)
                    atomicAdd(&gmean[b * CH + o0 + wm + mi * 16 + quad * 4 + r], v);
            }
    } else {
        if (mt < 4) {
            // ctx[b][o] += sum_n relu * mask[n]
            float mk[4];
#pragma unroll
            for (int nj = 0; nj < 4; ++nj)
                mk[nj] = maskp[(size_t)b * HW + n0 + wn + nj * 16 + lr];
#pragma unroll
            for (int mi = 0; mi < 4; ++mi)
#pragma unroll
                for (int r = 0; r < 4; ++r) {
                    float v = 0.f;
#pragma unroll
                    for (int nj = 0; nj < 4; ++nj)
                        v += fmaxf(acc[mi][nj][r], 0.f) * mk[nj];
                    v += __shfl_xor(v, 1); v += __shfl_xor(v, 2);
                    v += __shfl_xor(v, 4); v += __shfl_xor(v, 8);
                    if (lr == 0)
                        atomicAdd(&ctx[b * CH + o0 + wm + mi * 16 + quad * 4 + r], v);
                }
        } else {
            // cattnp[b][n] += sum_m relu * avgx[m]   (m-rows 512.. -> avgx idx o0-512)
            float colsum[4] = {0.f, 0.f, 0.f, 0.f};
#pragma unroll
            for (int mi = 0; mi < 4; ++mi) {
                float aw[4];
#pragma unroll
                for (int r = 0; r < 4; ++r)
                    aw[r] = avgx[b * CH + (o0 - 512) + wm + mi * 16 + quad * 4 + r];
#pragma unroll
                for (int nj = 0; nj < 4; ++nj)
#pragma unroll
                    for (int r = 0; r < 4; ++r)
                        colsum[nj] += fmaxf(acc[mi][nj][r], 0.f) * aw[r];
            }
#pragma unroll
            for (int nj = 0; nj < 4; ++nj) {
                float v = colsum[nj];
                v += __shfl_xor(v, 16);
                v += __shfl_xor(v, 32);
                if (lane < 16)
                    atomicAdd(&cattnp[(size_t)b * HW + n0 + wn + nj * 16 + lane], v);
            }
        }
    }
}

// softmax over hw (4096) per batch, in place; input is PRE-relu sums, so
// apply relu on read (max over relu'd values == fmax(raw, 0) fold).
__global__ __launch_bounds__(256) void softmax_hw_k(float* __restrict__ m)
{
    const int b = blockIdx.x;
    float* row = m + (size_t)b * HW;
    __shared__ float red[256];
    const int tid = threadIdx.x;
    float mx = 0.f;                                  // relu floor
    for (int i = tid; i < HW; i += 256) mx = fmaxf(mx, row[i]);
    red[tid] = mx; __syncthreads();
    for (int s = 128; s > 0; s >>= 1) { if (tid < s) red[tid] = fmaxf(red[tid], red[tid + s]); __syncthreads(); }
    mx = red[0]; __syncthreads();
    float sum = 0.f;
    for (int i = tid; i < HW; i += 256) { float e = __expf(fmaxf(row[i], 0.f) - mx); row[i] = e; sum += e; }
    red[tid] = sum; __syncthreads();
    for (int s = 128; s > 0; s >>= 1) { if (tid < s) red[tid] += red[tid + s]; __syncthreads(); }
    const float inv = 1.f / red[0];
    for (int i = tid; i < HW; i += 256) row[i] *= inv;
}

// gmean (spatial sums) -> /HW -> softmax over 512 channels -> avgx
__global__ __launch_bounds__(256) void softmax_ch_k(const float* __restrict__ gmean,
                                                    float* __restrict__ avgx)
{
    const int b = blockIdx.x;
    const float* src = gmean + b * CH;
    float* dst = avgx + b * CH;
    __shared__ float red[256];
    const int tid = threadIdx.x;
    const float v0 = src[tid]       * (1.f / HW);
    const float v1 = src[tid + 256] * (1.f / HW);
    red[tid] = fmaxf(v0, v1); __syncthreads();
    for (int s = 128; s > 0; s >>= 1) { if (tid < s) red[tid] = fmaxf(red[tid], red[tid + s]); __syncthreads(); }
    const float mx = red[0]; __syncthreads();
    const float e0 = __expf(v0 - mx), e1 = __expf(v1 - mx);
    red[tid] = e0 + e1; __syncthreads();
    for (int s = 128; s > 0; s >>= 1) { if (tid < s) red[tid] += red[tid + s]; __syncthreads(); }
    const float inv = 1.f / red[0];
    dst[tid] = e0 * inv; dst[tid + 256] = e1 * inv;
}

// layer_norm over 512 channels (no affine) -> sigmoid -> spatial_attn
__global__ __launch_bounds__(256) void ln_sig_k(const float* __restrict__ ctx,
                                                float* __restrict__ sattn)
{
    const int b = blockIdx.x;
    const float* src = ctx + b * CH;
    __shared__ float red[256];
    const int tid = threadIdx.x;
    const float v0 = src[tid], v1 = src[tid + 256];
    red[tid] = v0 + v1; __syncthreads();
    for (int s = 128; s > 0; s >>= 1) { if (tid < s) red[tid] += red[tid + s]; __syncthreads(); }
    const float mu = red[0] * (1.f / CH); __syncthreads();
    const float d0 = v0 - mu, d1 = v1 - mu;
    red[tid] = d0 * d0 + d1 * d1; __syncthreads();
    for (int s = 128; s > 0; s >>= 1) { if (tid < s) red[tid] += red[tid + s]; __syncthreads(); }
    const float rs = rsqrtf(red[0] * (1.f / CH) + LN_EPS);
    sattn[b * CH + tid]       = sigmoidf_(d0 * rs);
    sattn[b * CH + tid + 256] = sigmoidf_(d1 * rs);
}

// in-place sigmoid of cattnp (16x4096) so final_k doesn't recompute it x1024
__global__ __launch_bounds__(256) void sig_cattn_k(float* __restrict__ cattnp)
{
    const int i = blockIdx.x * 256 + threadIdx.x;
    cattnp[i] = sigmoidf_(cattnp[i]);
}

// out = x * (1 + attn); attn = c<512 ? sa[c]*cs[n] : sa[c-512]+cs[n]
// (cs = sigmoid(cattnp), precomputed)
__global__ __launch_bounds__(256) void final_k(const float* __restrict__ x,
                                               const float* __restrict__ sattn,
                                               const float* __restrict__ cattnp,
                                               float* __restrict__ out)
{
    const int c = blockIdx.x;   // 0..1023
    const int b = blockIdx.y;
    const float s = sattn[b * CH + (c & (CH - 1))];
    const bool seq = c < CH;
    const float4* xr = (const float4*)(x + ((size_t)b * CIN + c) * HW);
    const float4* cr = (const float4*)(cattnp + (size_t)b * HW);
    float4* orow = (float4*)(out + ((size_t)b * CIN + c) * HW);
    for (int i = threadIdx.x; i < HW / 4; i += 256) {
        const float4 xv = xr[i], cv = cr[i];
        float4 f;
        if (seq) { f.x = s * cv.x; f.y = s * cv.y; f.z = s * cv.z; f.w = s * cv.w; }
        else     { f.x = s + cv.x; f.y = s + cv.y; f.z = s + cv.z; f.w = s + cv.w; }
        float4 o;
        o.x = fmaf(xv.x, f.x, xv.x);
        o.y = fmaf(xv.y, f.y, xv.y);
        o.z = fmaf(xv.z, f.z, xv.z);
        o.w = fmaf(xv.w, f.w, xv.w);
        orow[i] = o;
    }
}

extern "C" void kernel_launch(void* const* d_in, const int* in_sizes, int n_in,
                              void* d_out, int out_size, void* d_ws, size_t ws_size,
                              hipStream_t stream)
{
    const float* x    = (const float*)d_in[0];
    const float* w_qr = (const float*)d_in[1];
    const float* w_vr = (const float*)d_in[2];
    const float* w_ql = (const float*)d_in[3];
    const float* w_vl = (const float*)d_in[4];
    float* out = (float*)d_out;

    // big scratch carved out of d_out (268 MB); all consumed before final_k writes
    unsigned short* xt = (unsigned short*)d_out;             // [b][n][c] bf16, 134 MB
    unsigned short* wA = xt + (size_t)BATCH * HW * CIN;      // 512*1024 bf16 (w_ql)
    unsigned short* wB = wA + 512 * CIN;                     // 1024*1024 bf16 (w_vr|w_vl)

    // small scratch in ws (~660 KB)
    float* ws     = (float*)d_ws;
    float* maskp  = ws;                      // 16*4096 (pre-relu sums -> softmax in place)
    float* avgx   = maskp + BATCH * HW;      // 16*512
    float* sattn  = avgx  + BATCH * CH;      // 16*512
    float* gmean  = sattn + BATCH * CH;      // 16*512
    float* ctx    = gmean + BATCH * CH;      // 16*512
    float* cattnp = ctx   + BATCH * CH;      // 16*4096

    // zero maskp (atomic target in transpose_convert) + gmean/ctx/cattnp
    hipMemsetAsync(maskp, 0,
                   (size_t)(BATCH * HW * 2 + BATCH * CH * 5) * sizeof(float), stream);

    wconvert<<<6144, 256, 0, stream>>>(w_vr, w_ql, w_vl, wA, wB);
    transpose_convert<<<dim3(HW / 64, CIN / 64, BATCH), 256, 0, stream>>>(
        x, w_qr, xt, maskp);

    mfma_gemm<<<dim3(HW / 128, 4, BATCH), 256, 0, stream>>>(
        xt, wA, 0, nullptr, nullptr, gmean, nullptr, nullptr);
    softmax_hw_k<<<BATCH, 256, 0, stream>>>(maskp);
    softmax_ch_k<<<BATCH, 256, 0, stream>>>(gmean, avgx);
    mfma_gemm<<<dim3(HW / 128, 8, BATCH), 256, 0, stream>>>(
        xt, wB, 1, maskp, avgx, nullptr, ctx, cattnp);
    ln_sig_k<<<BATCH, 256, 0, stream>>>(ctx, sattn);
    sig_cattn_k<<<BATCH * HW / 256, 256, 0, stream>>>(cattnp);
    final_k<<<dim3(CIN, BATCH), 256, 0, stream>>>(x, sattn, cattnp, out);
}

// Round 2
// 744.926 us; speedup vs baseline: 1.3180x; 1.3048x over previous
//
#include <hip/hip_runtime.h>
#include <cstdint>
#include <cstddef>

#define BATCH 16
#define CIN   1024
#define CH    512
#define HW    4096

static constexpr float LN_EPS = 1e-5f;

typedef __bf16 bf16x8 __attribute__((ext_vector_type(8)));
typedef float  f32x4  __attribute__((ext_vector_type(4)));

__device__ __forceinline__ float sigmoidf_(float v) { return 1.0f / (1.0f + __expf(-v)); }

// fp32 -> bf16 bits, round-to-nearest-even
__device__ __forceinline__ unsigned short f2bf(float f) {
    union { float f; uint32_t u; } c; c.f = f;
    uint32_t r = (c.u + 0x7fffu + ((c.u >> 16) & 1u)) >> 16;
    return (unsigned short)r;
}

#define GLOAD_LDS16(g, l)                                                  \
    __builtin_amdgcn_global_load_lds(                                      \
        (const __attribute__((address_space(1))) void*)(g),                \
        (__attribute__((address_space(3))) void*)(l), 16, 0, 0)

// ---------------------------------------------------------------------------
// x[b,c,n] fp32 -> xt[b,n,c] bf16; fused w_qr dot -> maskpre (atomic).
// ---------------------------------------------------------------------------
__global__ __launch_bounds__(256) void transpose_convert(
    const float* __restrict__ x, const float* __restrict__ wqr,
    unsigned short* __restrict__ xt, float* __restrict__ maskpre)
{
    const int b  = blockIdx.z;
    const int c0 = blockIdx.y * 64;
    const int n0 = blockIdx.x * 64;
    __shared__ float t[64][65];
    const int tid = threadIdx.x;
    const int tx = tid & 15, ty = tid >> 4;
    const float* xb = x + ((size_t)b * CIN + c0) * HW + n0;
#pragma unroll
    for (int rr = 0; rr < 4; ++rr) {
        const int row = ty + rr * 16;
        float4 v = *(const float4*)(xb + (size_t)row * HW + tx * 4);
        t[row][tx * 4 + 0] = v.x; t[row][tx * 4 + 1] = v.y;
        t[row][tx * 4 + 2] = v.z; t[row][tx * 4 + 3] = v.w;
    }
    __syncthreads();
    const int n  = tid >> 2;
    const int cp = (tid & 3) * 16;
    __align__(16) unsigned short tmp[16];
    float part = 0.f;
#pragma unroll
    for (int i = 0; i < 16; ++i) {
        const float v = t[cp + i][n];
        tmp[i] = f2bf(v);
        part = fmaf(wqr[c0 + cp + i], v, part);
    }
    unsigned short* dst = xt + ((size_t)b * HW + n0 + n) * CIN + c0 + cp;
    ((uint4*)dst)[0] = ((const uint4*)tmp)[0];
    ((uint4*)dst)[1] = ((const uint4*)tmp)[1];
    part += __shfl_xor(part, 1);
    part += __shfl_xor(part, 2);
    if ((tid & 3) == 0) atomicAdd(&maskpre[(size_t)b * HW + n0 + n], part);
}

// ---------------------------------------------------------------------------
// weight convert: wA (512 rows: w_ql), wB (1024 rows: w_vr[512] + w_vl[512])
// ---------------------------------------------------------------------------
__global__ __launch_bounds__(256) void wconvert(
    const float* __restrict__ wvr, const float* __restrict__ wql,
    const float* __restrict__ wvl,
    unsigned short* __restrict__ wA, unsigned short* __restrict__ wB)
{
    const int idx = blockIdx.x * 256 + threadIdx.x;
    if (idx < 512 * 1024) {
        wA[idx] = f2bf(wql[idx]);
    } else {
        const int j = idx - 512 * 1024;
        const int row = j >> 10, col = j & 1023;
        const float v = (row < 512) ? wvr[row * 1024 + col] : wvl[(row - 512) * 1024 + col];
        wB[j] = f2bf(v);
    }
}

// ---------------------------------------------------------------------------
// 256x256 tile, BK=64, 8-phase schedule (T2+T3+T4+T5), 512 thr / 8 waves.
// LDS 128KB: [buf(2)][mat A/B][half(2)] x 16KB, halves = 128 rows x 64 k bf16.
// Swizzle: 16B-slot index ^= (row&7), applied on BOTH stage-source and read.
// Per K-tile kt: 4 quadrant phases; stages: q0:A1(kt+1) q1:B0(kt+2)
// q2:B1(kt+2) q3:A0(kt+2); vmcnt(6) gate at q3 (drain 0 at kt=14).
// ---------------------------------------------------------------------------
__global__ __launch_bounds__(512) void mfma_gemm256(
    const unsigned short* __restrict__ xt,   // [b][n][c] bf16
    const unsigned short* __restrict__ wst,  // weights bf16 [o][c]
    const int MT, const int phase,
    const float* __restrict__ maskp,
    const float* __restrict__ avgx,
    float* __restrict__ gmean,
    float* __restrict__ ctx,
    float* __restrict__ cattnp)
{
    // XCD-chunked bijective remap (nwg % 8 == 0); mt innermost -> the MT
    // blocks sharing one xt tile are adjacent on the same XCD (L2 reuse).
    const int nwg = gridDim.x;
    const int per = nwg >> 3;
    const int bid = blockIdx.x;
    const int nid = (bid & 7) * per + (bid >> 3);
    const int mt = nid % MT;
    const int r2 = nid / MT;
    const int nb = r2 & 15;
    const int b  = r2 >> 4;
    const int o0 = mt * 256;
    const int n0 = nb * 256;

    const int tid  = threadIdx.x;
    const int w    = tid >> 6;
    const int lane = tid & 63;
    const int wm = w >> 2;        // 0..1  (M warp group, 128 rows each)
    const int wn = w & 3;         // 0..3  (N warp group, 64 cols each)
    const int lr = lane & 15;
    const int hi = lane >> 4;
    const int lr7 = lane & 7;

    __shared__ __align__(16) unsigned short lds[2 * 2 * 2 * 8192];  // 128 KiB

    f32x4 acc[8][4];
#pragma unroll
    for (int mi = 0; mi < 8; ++mi)
#pragma unroll
        for (int nj = 0; nj < 4; ++nj) acc[mi][nj] = (f32x4){0.f, 0.f, 0.f, 0.f};

    // ---- staging source pointers (per-lane, inverse-swizzled slot) ----
    const int sr  = lane >> 3;                 // row within 8-row chunk
    const int ssl = (lane & 7) ^ sr;           // swizzled source 16B-slot
    const unsigned short* gA[2][2];
    const unsigned short* gB[2][2];
#pragma unroll
    for (int h = 0; h < 2; ++h)
#pragma unroll
        for (int j = 0; j < 2; ++j) {
            const int row = (w * 2 + j) * 8 + sr;
            gA[h][j] = wst + (size_t)(o0 + h * 128 + row) * CIN + ssl * 8;
            gB[h][j] = xt + ((size_t)b * HW + n0 + h * 128 + row) * CIN + ssl * 8;
        }

    // stage one half-tile (matrix m, half h, K-tile tt): 2 x 1KB per wave,
    // LDS dest is wave-uniform (HW adds lane*16).
#define STG(m, h, tt) do {                                                  \
        unsigned short* lb_ = lds + ((((tt) & 1) * 4) + (m) * 2 + (h)) * 8192 \
                              + (w * 2) * 512;                              \
        const unsigned short* s0_ = ((m) ? gB[h][0] : gA[h][0]) + (tt) * 64; \
        const unsigned short* s1_ = ((m) ? gB[h][1] : gA[h][1]) + (tt) * 64; \
        GLOAD_LDS16(s0_, lb_);                                              \
        GLOAD_LDS16(s1_, lb_ + 512);                                        \
    } while (0)

    // ---- read offsets (shorts), swizzled slot = (s*4+hi) ^ (lr&7) ----
    const int aoff = lr * 64;
    const int boff = (wn & 1) * 4096 + lr * 64;
    const int sl0 = ((0 + hi) ^ lr7) * 8;
    const int sl1 = ((4 + hi) ^ lr7) * 8;

    bf16x8 bf[4][2];

#define PHASE_BODY(q, c, STAGE_STMT, GATE_STMT) do {                        \
        const unsigned short* Ab_ = lds + ((c) * 4 + wm) * 8192;            \
        const unsigned short* Bb_ = lds + ((c) * 4 + 2 + (wn >> 1)) * 8192; \
        if ((q) == 0) {                                                     \
            _Pragma("unroll")                                               \
            for (int nj = 0; nj < 4; ++nj) {                                \
                bf[nj][0] = *(const bf16x8*)(Bb_ + boff + nj * 1024 + sl0); \
                bf[nj][1] = *(const bf16x8*)(Bb_ + boff + nj * 1024 + sl1); \
            }                                                               \
        }                                                                   \
        bf16x8 af_[2][2];                                                   \
        _Pragma("unroll")                                                   \
        for (int mi = 0; mi < 2; ++mi) {                                    \
            af_[mi][0] = *(const bf16x8*)(Ab_ + ((q) * 32 + mi * 16) * 64 + aoff + sl0); \
            af_[mi][1] = *(const bf16x8*)(Ab_ + ((q) * 32 + mi * 16) * 64 + aoff + sl1); \
        }                                                                   \
        STAGE_STMT;                                                         \
        GATE_STMT;                                                          \
        asm volatile("s_barrier" ::: "memory");                             \
        __builtin_amdgcn_s_setprio(1);                                      \
        _Pragma("unroll")                                                   \
        for (int mi = 0; mi < 2; ++mi)                                      \
            _Pragma("unroll")                                               \
            for (int nj = 0; nj < 4; ++nj) {                                \
                acc[(q) * 2 + mi][nj] = __builtin_amdgcn_mfma_f32_16x16x32_bf16( \
                    af_[mi][0], bf[nj][0], acc[(q) * 2 + mi][nj], 0, 0, 0); \
                acc[(q) * 2 + mi][nj] = __builtin_amdgcn_mfma_f32_16x16x32_bf16( \
                    af_[mi][1], bf[nj][1], acc[(q) * 2 + mi][nj], 0, 0, 0); \
            }                                                               \
        __builtin_amdgcn_s_setprio(0);                                      \
        __builtin_amdgcn_sched_barrier(0);                                  \
        asm volatile("s_barrier" ::: "memory");                             \
    } while (0)

    // ---- prologue: tile0 {A0,A1,B0,B1}, tile1 {B0,B1,A0}; A1(1) in-loop ----
    STG(0, 0, 0); STG(0, 1, 0); STG(1, 0, 0); STG(1, 1, 0);
    STG(1, 0, 1); STG(1, 1, 1); STG(0, 0, 1);
    asm volatile("s_waitcnt vmcnt(6)" ::: "memory");
    asm volatile("s_barrier" ::: "memory");

#pragma unroll 2
    for (int kt = 0; kt < 16; ++kt) {
        const int c = kt & 1;
        PHASE_BODY(0, c, { if (kt < 15) STG(0, 1, kt + 1); }, {});
        PHASE_BODY(1, c, { if (kt < 14) STG(1, 0, kt + 2); }, {});
        PHASE_BODY(2, c, { if (kt < 14) STG(1, 1, kt + 2); }, {});
        PHASE_BODY(3, c, { if (kt < 14) STG(0, 0, kt + 2); },
                   { if (kt < 14)       asm volatile("s_waitcnt vmcnt(6)" ::: "memory");
                     else if (kt == 14) asm volatile("s_waitcnt vmcnt(0)" ::: "memory"); });
    }
#undef PHASE_BODY
#undef STG

    // ---- epilogues (C/D: col = lr, row = wm*128 + mrow*16 + quad*4 + reg) ----
    const int quad = hi;
    if (phase == 0) {
        // gmean[b][o] += sum_n relu
#pragma unroll
        for (int mr = 0; mr < 8; ++mr)
#pragma unroll
            for (int r = 0; r < 4; ++r) {
                float v = 0.f;
#pragma unroll
                for (int nj = 0; nj < 4; ++nj) v += fmaxf(acc[mr][nj][r], 0.f);
                v += __shfl_xor(v, 1); v += __shfl_xor(v, 2);
                v += __shfl_xor(v, 4); v += __shfl_xor(v, 8);
                if (lr == 0)
                    atomicAdd(&gmean[b * CH + o0 + wm * 128 + mr * 16 + quad * 4 + r], v);
            }
    } else if (mt < 2) {
        // ctx[b][o] += sum_n relu * mask[n]
        float mk[4];
#pragma unroll
        for (int nj = 0; nj < 4; ++nj)
            mk[nj] = maskp[(size_t)b * HW + n0 + wn * 64 + nj * 16 + lr];
#pragma unroll
        for (int mr = 0; mr < 8; ++mr)
#pragma unroll
            for (int r = 0; r < 4; ++r) {
                float v = 0.f;
#pragma unroll
                for (int nj = 0; nj < 4; ++nj)
                    v += fmaxf(acc[mr][nj][r], 0.f) * mk[nj];
                v += __shfl_xor(v, 1); v += __shfl_xor(v, 2);
                v += __shfl_xor(v, 4); v += __shfl_xor(v, 8);
                if (lr == 0)
                    atomicAdd(&ctx[b * CH + o0 + wm * 128 + mr * 16 + quad * 4 + r], v);
            }
    } else {
        // cattnp[b][n] += sum_m relu * avgx[m]   (vl rows: avgx idx o0-512)
        float colsum[4] = {0.f, 0.f, 0.f, 0.f};
#pragma unroll
        for (int mr = 0; mr < 8; ++mr) {
            float aw[4];
#pragma unroll
            for (int r = 0; r < 4; ++r)
                aw[r] = avgx[b * CH + (o0 - 512) + wm * 128 + mr * 16 + quad * 4 + r];
#pragma unroll
            for (int nj = 0; nj < 4; ++nj)
#pragma unroll
                for (int r = 0; r < 4; ++r)
                    colsum[nj] += fmaxf(acc[mr][nj][r], 0.f) * aw[r];
        }
#pragma unroll
        for (int nj = 0; nj < 4; ++nj) {
            float v = colsum[nj];
            v += __shfl_xor(v, 16);
            v += __shfl_xor(v, 32);
            if (lane < 16)
                atomicAdd(&cattnp[(size_t)b * HW + n0 + wn * 64 + nj * 16 + lane], v);
        }
    }
}

// softmax over hw (4096) per batch, in place; input is PRE-relu sums.
__global__ __launch_bounds__(256) void softmax_hw_k(float* __restrict__ m)
{
    const int b = blockIdx.x;
    float* row = m + (size_t)b * HW;
    __shared__ float red[256];
    const int tid = threadIdx.x;
    float mx = 0.f;
    for (int i = tid; i < HW; i += 256) mx = fmaxf(mx, row[i]);
    red[tid] = mx; __syncthreads();
    for (int s = 128; s > 0; s >>= 1) { if (tid < s) red[tid] = fmaxf(red[tid], red[tid + s]); __syncthreads(); }
    mx = red[0]; __syncthreads();
    float sum = 0.f;
    for (int i = tid; i < HW; i += 256) { float e = __expf(fmaxf(row[i], 0.f) - mx); row[i] = e; sum += e; }
    red[tid] = sum; __syncthreads();
    for (int s = 128; s > 0; s >>= 1) { if (tid < s) red[tid] += red[tid + s]; __syncthreads(); }
    const float inv = 1.f / red[0];
    for (int i = tid; i < HW; i += 256) row[i] *= inv;
}

// gmean (spatial sums) -> /HW -> softmax over 512 channels -> avgx
__global__ __launch_bounds__(256) void softmax_ch_k(const float* __restrict__ gmean,
                                                    float* __restrict__ avgx)
{
    const int b = blockIdx.x;
    const float* src = gmean + b * CH;
    float* dst = avgx + b * CH;
    __shared__ float red[256];
    const int tid = threadIdx.x;
    const float v0 = src[tid]       * (1.f / HW);
    const float v1 = src[tid + 256] * (1.f / HW);
    red[tid] = fmaxf(v0, v1); __syncthreads();
    for (int s = 128; s > 0; s >>= 1) { if (tid < s) red[tid] = fmaxf(red[tid], red[tid + s]); __syncthreads(); }
    const float mx = red[0]; __syncthreads();
    const float e0 = __expf(v0 - mx), e1 = __expf(v1 - mx);
    red[tid] = e0 + e1; __syncthreads();
    for (int s = 128; s > 0; s >>= 1) { if (tid < s) red[tid] += red[tid + s]; __syncthreads(); }
    const float inv = 1.f / red[0];
    dst[tid] = e0 * inv; dst[tid + 256] = e1 * inv;
}

// layer_norm over 512 channels (no affine) -> sigmoid -> spatial_attn
__global__ __launch_bounds__(256) void ln_sig_k(const float* __restrict__ ctx,
                                                float* __restrict__ sattn)
{
    const int b = blockIdx.x;
    const float* src = ctx + b * CH;
    __shared__ float red[256];
    const int tid = threadIdx.x;
    const float v0 = src[tid], v1 = src[tid + 256];
    red[tid] = v0 + v1; __syncthreads();
    for (int s = 128; s > 0; s >>= 1) { if (tid < s) red[tid] += red[tid + s]; __syncthreads(); }
    const float mu = red[0] * (1.f / CH); __syncthreads();
    const float d0 = v0 - mu, d1 = v1 - mu;
    red[tid] = d0 * d0 + d1 * d1; __syncthreads();
    for (int s = 128; s > 0; s >>= 1) { if (tid < s) red[tid] += red[tid + s]; __syncthreads(); }
    const float rs = rsqrtf(red[0] * (1.f / CH) + LN_EPS);
    sattn[b * CH + tid]       = sigmoidf_(d0 * rs);
    sattn[b * CH + tid + 256] = sigmoidf_(d1 * rs);
}

// in-place sigmoid of cattnp (16x4096)
__global__ __launch_bounds__(256) void sig_cattn_k(float* __restrict__ cattnp)
{
    const int i = blockIdx.x * 256 + threadIdx.x;
    cattnp[i] = sigmoidf_(cattnp[i]);
}

// out = x * (1 + attn); attn = c<512 ? sa[c]*cs[n] : sa[c-512]+cs[n]
__global__ __launch_bounds__(256) void final_k(const float* __restrict__ x,
                                               const float* __restrict__ sattn,
                                               const float* __restrict__ cattnp,
                                               float* __restrict__ out)
{
    const int c = blockIdx.x;
    const int b = blockIdx.y;
    const float s = sattn[b * CH + (c & (CH - 1))];
    const bool seq = c < CH;
    const float4* xr = (const float4*)(x + ((size_t)b * CIN + c) * HW);
    const float4* cr = (const float4*)(cattnp + (size_t)b * HW);
    float4* orow = (float4*)(out + ((size_t)b * CIN + c) * HW);
    for (int i = threadIdx.x; i < HW / 4; i += 256) {
        const float4 xv = xr[i], cv = cr[i];
        float4 f;
        if (seq) { f.x = s * cv.x; f.y = s * cv.y; f.z = s * cv.z; f.w = s * cv.w; }
        else     { f.x = s + cv.x; f.y = s + cv.y; f.z = s + cv.z; f.w = s + cv.w; }
        float4 o;
        o.x = fmaf(xv.x, f.x, xv.x);
        o.y = fmaf(xv.y, f.y, xv.y);
        o.z = fmaf(xv.z, f.z, xv.z);
        o.w = fmaf(xv.w, f.w, xv.w);
        orow[i] = o;
    }
}

extern "C" void kernel_launch(void* const* d_in, const int* in_sizes, int n_in,
                              void* d_out, int out_size, void* d_ws, size_t ws_size,
                              hipStream_t stream)
{
    const float* x    = (const float*)d_in[0];
    const float* w_qr = (const float*)d_in[1];
    const float* w_vr = (const float*)d_in[2];
    const float* w_ql = (const float*)d_in[3];
    const float* w_vl = (const float*)d_in[4];
    float* out = (float*)d_out;

    // big scratch carved out of d_out; all consumed before final_k writes
    unsigned short* xt = (unsigned short*)d_out;             // [b][n][c] bf16, 134 MB
    unsigned short* wA = xt + (size_t)BATCH * HW * CIN;      // 512*1024 bf16 (w_ql)
    unsigned short* wB = wA + 512 * CIN;                     // 1024*1024 bf16 (w_vr|w_vl)

    float* ws     = (float*)d_ws;
    float* maskp  = ws;                      // 16*4096
    float* avgx   = maskp + BATCH * HW;      // 16*512
    float* sattn  = avgx  + BATCH * CH;      // 16*512
    float* gmean  = sattn + BATCH * CH;      // 16*512
    float* ctx    = gmean + BATCH * CH;      // 16*512
    float* cattnp = ctx   + BATCH * CH;      // 16*4096

    hipMemsetAsync(maskp, 0,
                   (size_t)(BATCH * HW * 2 + BATCH * CH * 5) * sizeof(float), stream);

    wconvert<<<6144, 256, 0, stream>>>(w_vr, w_ql, w_vl, wA, wB);
    transpose_convert<<<dim3(HW / 64, CIN / 64, BATCH), 256, 0, stream>>>(
        x, w_qr, xt, maskp);

    // phase 0: MT=2 (w_ql rows 0..511) -> 512 blocks
    mfma_gemm256<<<512, 512, 0, stream>>>(
        xt, wA, 2, 0, nullptr, nullptr, gmean, nullptr, nullptr);
    softmax_hw_k<<<BATCH, 256, 0, stream>>>(maskp);
    softmax_ch_k<<<BATCH, 256, 0, stream>>>(gmean, avgx);
    // phase 1: MT=4 (w_vr|w_vl rows 0..1023) -> 1024 blocks
    mfma_gemm256<<<1024, 512, 0, stream>>>(
        xt, wB, 4, 1, maskp, avgx, nullptr, ctx, cattnp);
    ln_sig_k<<<BATCH, 256, 0, stream>>>(ctx, sattn);
    sig_cattn_k<<<BATCH * HW / 256, 256, 0, stream>>>(cattnp);
    final_k<<<dim3(CIN, BATCH), 256, 0, stream>>>(x, sattn, cattnp, out);
}

// Round 3
// 721.425 us; speedup vs baseline: 1.3609x; 1.0326x over previous
//
#include <hip/hip_runtime.h>
#include <cstdint>
#include <cstddef>

#define BATCH 16
#define CIN   1024
#define CH    512
#define HW    4096

static constexpr float LN_EPS = 1e-5f;

typedef __bf16 bf16x8 __attribute__((ext_vector_type(8)));
typedef float  f32x4  __attribute__((ext_vector_type(4)));

__device__ __forceinline__ float sigmoidf_(float v) { return 1.0f / (1.0f + __expf(-v)); }

// fp32 -> bf16 bits, round-to-nearest-even
__device__ __forceinline__ unsigned short f2bf(float f) {
    union { float f; uint32_t u; } c; c.f = f;
    uint32_t r = (c.u + 0x7fffu + ((c.u >> 16) & 1u)) >> 16;
    return (unsigned short)r;
}

#define GLOAD_LDS16(g, l)                                                  \
    __builtin_amdgcn_global_load_lds(                                      \
        (const __attribute__((address_space(1))) void*)(g),                \
        (__attribute__((address_space(3))) void*)(l), 16, 0, 0)

// ---------------------------------------------------------------------------
// prep: blocks [0,16384): x[b,c,n] fp32 -> xt[b,n,c] bf16 + fused w_qr dot
//       -> maskpre (atomic).  blocks [16384, 22528): weight convert:
//       wA = [w_ql(512); w_vr(512)] bf16, wB = w_vl(512) bf16.
// ---------------------------------------------------------------------------
__global__ __launch_bounds__(256) void prep_k(
    const float* __restrict__ x, const float* __restrict__ wqr,
    const float* __restrict__ wvr, const float* __restrict__ wql,
    const float* __restrict__ wvl,
    unsigned short* __restrict__ xt, float* __restrict__ maskpre,
    unsigned short* __restrict__ wA, unsigned short* __restrict__ wB)
{
    __shared__ float t[64][65];
    const int tid = threadIdx.x;
    if (blockIdx.x >= 16384) {
        const int j = (blockIdx.x - 16384) * 256 + tid;
        if (j < 1024 * 1024) {
            const int row = j >> 10, col = j & 1023;
            const float v = (row < 512) ? wql[row * 1024 + col]
                                        : wvr[(row - 512) * 1024 + col];
            wA[j] = f2bf(v);
        } else {
            const int k = j - 1024 * 1024;
            wB[k] = f2bf(wvl[k]);
        }
        return;
    }
    const int nb = blockIdx.x & 63;
    const int cb = (blockIdx.x >> 6) & 15;
    const int b  = blockIdx.x >> 10;
    const int c0 = cb * 64;
    const int n0 = nb * 64;
    const int tx = tid & 15, ty = tid >> 4;
    const float* xb = x + ((size_t)b * CIN + c0) * HW + n0;
#pragma unroll
    for (int rr = 0; rr < 4; ++rr) {
        const int row = ty + rr * 16;
        float4 v = *(const float4*)(xb + (size_t)row * HW + tx * 4);
        t[row][tx * 4 + 0] = v.x; t[row][tx * 4 + 1] = v.y;
        t[row][tx * 4 + 2] = v.z; t[row][tx * 4 + 3] = v.w;
    }
    __syncthreads();
    const int n  = tid >> 2;
    const int cp = (tid & 3) * 16;
    __align__(16) unsigned short tmp[16];
    float part = 0.f;
#pragma unroll
    for (int i = 0; i < 16; ++i) {
        const float v = t[cp + i][n];
        tmp[i] = f2bf(v);
        part = fmaf(wqr[c0 + cp + i], v, part);
    }
    unsigned short* dst = xt + ((size_t)b * HW + n0 + n) * CIN + c0 + cp;
    ((uint4*)dst)[0] = ((const uint4*)tmp)[0];
    ((uint4*)dst)[1] = ((const uint4*)tmp)[1];
    part += __shfl_xor(part, 1);
    part += __shfl_xor(part, 2);
    if ((tid & 3) == 0) atomicAdd(&maskpre[(size_t)b * HW + n0 + n], part);
}

// ---------------------------------------------------------------------------
// 256x256 tile, BK=64, 8-phase schedule (T2+T3+T4+T5), 512 thr / 8 waves.
// LDS 128KB: [buf(2)][mat A/B][half(2)] x 16KB, halves = 128 rows x 64 k bf16.
// Swizzle: 16B-slot index ^= (row&7), applied on BOTH stage-source and read.
// phase 0 (GEMM-A, wA = ql|vr, MT=4):
//   mt 0-1 -> gmean[b,o]  += sum_n relu           (ql rows)
//   mt 2-3 -> ctxu[b,o]   += sum_n relu * exp(relu(maskpre[n]))   (vr rows)
//             (deferred softmax normalization; LN divides by S later)
// phase 1 (GEMM-B, wB = vl, MT=2):
//   cattnp[b,n] += sum_m relu * avgx[m]
// ---------------------------------------------------------------------------
__global__ __launch_bounds__(512) void mfma_gemm256(
    const unsigned short* __restrict__ xt,   // [b][n][c] bf16
    const unsigned short* __restrict__ wst,  // weights bf16 [o][c]
    const int MT, const int phase,
    const float* __restrict__ maskp,         // raw maskpre (phase 0)
    const float* __restrict__ avgx,          // phase 1
    float* __restrict__ gmean,
    float* __restrict__ ctx,
    float* __restrict__ cattnp)
{
    // XCD-chunked bijective remap (nwg % 8 == 0); mt innermost -> the MT
    // blocks sharing one xt tile are adjacent on the same XCD (L2 reuse).
    const int nwg = gridDim.x;
    const int per = nwg >> 3;
    const int bid = blockIdx.x;
    const int nid = (bid & 7) * per + (bid >> 3);
    const int mt = nid % MT;
    const int r2 = nid / MT;
    const int nb = r2 & 15;
    const int b  = r2 >> 4;
    const int o0 = mt * 256;
    const int n0 = nb * 256;

    const int tid  = threadIdx.x;
    const int w    = tid >> 6;
    const int lane = tid & 63;
    const int wm = w >> 2;        // 0..1  (M warp group, 128 rows each)
    const int wn = w & 3;         // 0..3  (N warp group, 64 cols each)
    const int lr = lane & 15;
    const int hi = lane >> 4;
    const int lr7 = lane & 7;

    __shared__ __align__(16) unsigned short lds[2 * 2 * 2 * 8192];  // 128 KiB

    f32x4 acc[8][4];
#pragma unroll
    for (int mi = 0; mi < 8; ++mi)
#pragma unroll
        for (int nj = 0; nj < 4; ++nj) acc[mi][nj] = (f32x4){0.f, 0.f, 0.f, 0.f};

    // ---- staging source pointers (per-lane, inverse-swizzled slot) ----
    const int sr  = lane >> 3;                 // row within 8-row chunk
    const int ssl = (lane & 7) ^ sr;           // swizzled source 16B-slot
    const unsigned short* gA[2][2];
    const unsigned short* gB[2][2];
#pragma unroll
    for (int h = 0; h < 2; ++h)
#pragma unroll
        for (int j = 0; j < 2; ++j) {
            const int row = (w * 2 + j) * 8 + sr;
            gA[h][j] = wst + (size_t)(o0 + h * 128 + row) * CIN + ssl * 8;
            gB[h][j] = xt + ((size_t)b * HW + n0 + h * 128 + row) * CIN + ssl * 8;
        }

#define STG(m, h, tt) do {                                                  \
        unsigned short* lb_ = lds + ((((tt) & 1) * 4) + (m) * 2 + (h)) * 8192 \
                              + (w * 2) * 512;                              \
        const unsigned short* s0_ = ((m) ? gB[h][0] : gA[h][0]) + (tt) * 64; \
        const unsigned short* s1_ = ((m) ? gB[h][1] : gA[h][1]) + (tt) * 64; \
        GLOAD_LDS16(s0_, lb_);                                              \
        GLOAD_LDS16(s1_, lb_ + 512);                                        \
    } while (0)

    // ---- read offsets (shorts), swizzled slot = (s*4+hi) ^ (lr&7) ----
    const int aoff = lr * 64;
    const int boff = (wn & 1) * 4096 + lr * 64;
    const int sl0 = ((0 + hi) ^ lr7) * 8;
    const int sl1 = ((4 + hi) ^ lr7) * 8;

    bf16x8 bf[4][2];

#define PHASE_BODY(q, c, STAGE_STMT, GATE_STMT) do {                        \
        const unsigned short* Ab_ = lds + ((c) * 4 + wm) * 8192;            \
        const unsigned short* Bb_ = lds + ((c) * 4 + 2 + (wn >> 1)) * 8192; \
        if ((q) == 0) {                                                     \
            _Pragma("unroll")                                               \
            for (int nj = 0; nj < 4; ++nj) {                                \
                bf[nj][0] = *(const bf16x8*)(Bb_ + boff + nj * 1024 + sl0); \
                bf[nj][1] = *(const bf16x8*)(Bb_ + boff + nj * 1024 + sl1); \
            }                                                               \
        }                                                                   \
        bf16x8 af_[2][2];                                                   \
        _Pragma("unroll")                                                   \
        for (int mi = 0; mi < 2; ++mi) {                                    \
            af_[mi][0] = *(const bf16x8*)(Ab_ + ((q) * 32 + mi * 16) * 64 + aoff + sl0); \
            af_[mi][1] = *(const bf16x8*)(Ab_ + ((q) * 32 + mi * 16) * 64 + aoff + sl1); \
        }                                                                   \
        STAGE_STMT;                                                         \
        GATE_STMT;                                                          \
        asm volatile("s_barrier" ::: "memory");                             \
        __builtin_amdgcn_s_setprio(1);                                      \
        _Pragma("unroll")                                                   \
        for (int mi = 0; mi < 2; ++mi)                                      \
            _Pragma("unroll")                                               \
            for (int nj = 0; nj < 4; ++nj) {                                \
                acc[(q) * 2 + mi][nj] = __builtin_amdgcn_mfma_f32_16x16x32_bf16( \
                    af_[mi][0], bf[nj][0], acc[(q) * 2 + mi][nj], 0, 0, 0); \
                acc[(q) * 2 + mi][nj] = __builtin_amdgcn_mfma_f32_16x16x32_bf16( \
                    af_[mi][1], bf[nj][1], acc[(q) * 2 + mi][nj], 0, 0, 0); \
            }                                                               \
        __builtin_amdgcn_s_setprio(0);                                      \
        __builtin_amdgcn_sched_barrier(0);                                  \
        asm volatile("s_barrier" ::: "memory");                             \
    } while (0)

    // ---- prologue: tile0 {A0,A1,B0,B1}, tile1 {B0,B1,A0}; A1(1) in-loop ----
    STG(0, 0, 0); STG(0, 1, 0); STG(1, 0, 0); STG(1, 1, 0);
    STG(1, 0, 1); STG(1, 1, 1); STG(0, 0, 1);
    asm volatile("s_waitcnt vmcnt(6)" ::: "memory");
    asm volatile("s_barrier" ::: "memory");

#pragma unroll 2
    for (int kt = 0; kt < 16; ++kt) {
        const int c = kt & 1;
        PHASE_BODY(0, c, { if (kt < 15) STG(0, 1, kt + 1); }, {});
        PHASE_BODY(1, c, { if (kt < 14) STG(1, 0, kt + 2); }, {});
        PHASE_BODY(2, c, { if (kt < 14) STG(1, 1, kt + 2); }, {});
        PHASE_BODY(3, c, { if (kt < 14) STG(0, 0, kt + 2); },
                   { if (kt < 14)       asm volatile("s_waitcnt vmcnt(6)" ::: "memory");
                     else if (kt == 14) asm volatile("s_waitcnt vmcnt(0)" ::: "memory"); });
    }
#undef PHASE_BODY
#undef STG

    // ---- epilogues (C/D: col = lr, row = wm*128 + mr*16 + quad*4 + reg) ----
    const int quad = hi;
    if (phase == 0) {
        if (mt < 2) {
            // gmean[b][o] += sum_n relu
#pragma unroll
            for (int mr = 0; mr < 8; ++mr)
#pragma unroll
                for (int r = 0; r < 4; ++r) {
                    float v = 0.f;
#pragma unroll
                    for (int nj = 0; nj < 4; ++nj) v += fmaxf(acc[mr][nj][r], 0.f);
                    v += __shfl_xor(v, 1); v += __shfl_xor(v, 2);
                    v += __shfl_xor(v, 4); v += __shfl_xor(v, 8);
                    if (lr == 0)
                        atomicAdd(&gmean[b * CH + o0 + wm * 128 + mr * 16 + quad * 4 + r], v);
                }
        } else {
            // ctxu[b][o] += sum_n relu * exp(relu(maskpre[n]))  (unnormalized)
            float ew[4];
#pragma unroll
            for (int nj = 0; nj < 4; ++nj)
                ew[nj] = __expf(fmaxf(maskp[(size_t)b * HW + n0 + wn * 64 + nj * 16 + lr], 0.f));
#pragma unroll
            for (int mr = 0; mr < 8; ++mr)
#pragma unroll
                for (int r = 0; r < 4; ++r) {
                    float v = 0.f;
#pragma unroll
                    for (int nj = 0; nj < 4; ++nj)
                        v += fmaxf(acc[mr][nj][r], 0.f) * ew[nj];
                    v += __shfl_xor(v, 1); v += __shfl_xor(v, 2);
                    v += __shfl_xor(v, 4); v += __shfl_xor(v, 8);
                    if (lr == 0)
                        atomicAdd(&ctx[b * CH + (o0 - 512) + wm * 128 + mr * 16 + quad * 4 + r], v);
                }
        }
    } else {
        // cattnp[b][n] += sum_m relu * avgx[m]
        float colsum[4] = {0.f, 0.f, 0.f, 0.f};
#pragma unroll
        for (int mr = 0; mr < 8; ++mr) {
            float aw[4];
#pragma unroll
            for (int r = 0; r < 4; ++r)
                aw[r] = avgx[b * CH + o0 + wm * 128 + mr * 16 + quad * 4 + r];
#pragma unroll
            for (int nj = 0; nj < 4; ++nj)
#pragma unroll
                for (int r = 0; r < 4; ++r)
                    colsum[nj] += fmaxf(acc[mr][nj][r], 0.f) * aw[r];
        }
#pragma unroll
        for (int nj = 0; nj < 4; ++nj) {
            float v = colsum[nj];
            v += __shfl_xor(v, 16);
            v += __shfl_xor(v, 32);
            if (lane < 16)
                atomicAdd(&cattnp[(size_t)b * HW + n0 + wn * 64 + nj * 16 + lane], v);
        }
    }
}

// blocks 0..15: gmean -> /HW -> softmax over 512 ch -> avgx
// blocks 16..31: S[b] = sum_n exp(relu(maskpre[b,n]))  (softmax denominator)
__global__ __launch_bounds__(256) void smch_S_k(const float* __restrict__ gmean,
                                                const float* __restrict__ maskp,
                                                float* __restrict__ avgx,
                                                float* __restrict__ sden)
{
    __shared__ float red[256];
    const int tid = threadIdx.x;
    if (blockIdx.x < 16) {
        const int b = blockIdx.x;
        const float* src = gmean + b * CH;
        float* dst = avgx + b * CH;
        const float v0 = src[tid]       * (1.f / HW);
        const float v1 = src[tid + 256] * (1.f / HW);
        red[tid] = fmaxf(v0, v1); __syncthreads();
        for (int s = 128; s > 0; s >>= 1) { if (tid < s) red[tid] = fmaxf(red[tid], red[tid + s]); __syncthreads(); }
        const float mx = red[0]; __syncthreads();
        const float e0 = __expf(v0 - mx), e1 = __expf(v1 - mx);
        red[tid] = e0 + e1; __syncthreads();
        for (int s = 128; s > 0; s >>= 1) { if (tid < s) red[tid] += red[tid + s]; __syncthreads(); }
        const float inv = 1.f / red[0];
        dst[tid] = e0 * inv; dst[tid + 256] = e1 * inv;
    } else {
        const int b = blockIdx.x - 16;
        const float* row = maskp + (size_t)b * HW;
        float s = 0.f;
        for (int i = tid; i < HW; i += 256) s += __expf(fmaxf(row[i], 0.f));
        red[tid] = s; __syncthreads();
        for (int st = 128; st > 0; st >>= 1) { if (tid < st) red[tid] += red[tid + st]; __syncthreads(); }
        if (tid == 0) sden[b] = red[0];
    }
}

// blocks 0..15: layer_norm(ctxu / S[b]) -> sigmoid -> sattn
// blocks 16..271: cattnp -> sigmoid in place
__global__ __launch_bounds__(256) void lnsig_k(const float* __restrict__ ctx,
                                               const float* __restrict__ sden,
                                               float* __restrict__ sattn,
                                               float* __restrict__ cattnp)
{
    const int tid = threadIdx.x;
    if (blockIdx.x >= 16) {
        const int i = (blockIdx.x - 16) * 256 + tid;
        cattnp[i] = sigmoidf_(cattnp[i]);
        return;
    }
    const int b = blockIdx.x;
    const float invS = 1.f / sden[b];
    const float* src = ctx + b * CH;
    __shared__ float red[256];
    const float v0 = src[tid] * invS, v1 = src[tid + 256] * invS;
    red[tid] = v0 + v1; __syncthreads();
    for (int s = 128; s > 0; s >>= 1) { if (tid < s) red[tid] += red[tid + s]; __syncthreads(); }
    const float mu = red[0] * (1.f / CH); __syncthreads();
    const float d0 = v0 - mu, d1 = v1 - mu;
    red[tid] = d0 * d0 + d1 * d1; __syncthreads();
    for (int s = 128; s > 0; s >>= 1) { if (tid < s) red[tid] += red[tid + s]; __syncthreads(); }
    const float rs = rsqrtf(red[0] * (1.f / CH) + LN_EPS);
    sattn[b * CH + tid]       = sigmoidf_(d0 * rs);
    sattn[b * CH + tid + 256] = sigmoidf_(d1 * rs);
}

// out = x * (1 + attn); attn = c<512 ? sa[c]*cs[n] : sa[c-512]+cs[n]
__global__ __launch_bounds__(256) void final_k(const float* __restrict__ x,
                                               const float* __restrict__ sattn,
                                               const float* __restrict__ cattnp,
                                               float* __restrict__ out)
{
    const int c = blockIdx.x;
    const int b = blockIdx.y;
    const float s = sattn[b * CH + (c & (CH - 1))];
    const bool seq = c < CH;
    const float4* xr = (const float4*)(x + ((size_t)b * CIN + c) * HW);
    const float4* cr = (const float4*)(cattnp + (size_t)b * HW);
    float4* orow = (float4*)(out + ((size_t)b * CIN + c) * HW);
    for (int i = threadIdx.x; i < HW / 4; i += 256) {
        const float4 xv = xr[i], cv = cr[i];
        float4 f;
        if (seq) { f.x = s * cv.x; f.y = s * cv.y; f.z = s * cv.z; f.w = s * cv.w; }
        else     { f.x = s + cv.x; f.y = s + cv.y; f.z = s + cv.z; f.w = s + cv.w; }
        float4 o;
        o.x = fmaf(xv.x, f.x, xv.x);
        o.y = fmaf(xv.y, f.y, xv.y);
        o.z = fmaf(xv.z, f.z, xv.z);
        o.w = fmaf(xv.w, f.w, xv.w);
        orow[i] = o;
    }
}

extern "C" void kernel_launch(void* const* d_in, const int* in_sizes, int n_in,
                              void* d_out, int out_size, void* d_ws, size_t ws_size,
                              hipStream_t stream)
{
    const float* x    = (const float*)d_in[0];
    const float* w_qr = (const float*)d_in[1];
    const float* w_vr = (const float*)d_in[2];
    const float* w_ql = (const float*)d_in[3];
    const float* w_vl = (const float*)d_in[4];
    float* out = (float*)d_out;

    // big scratch carved out of d_out; all consumed before final_k writes
    unsigned short* xt = (unsigned short*)d_out;             // [b][n][c] bf16, 134 MB
    unsigned short* wA = xt + (size_t)BATCH * HW * CIN;      // 1024*1024 bf16 (ql|vr)
    unsigned short* wB = wA + 1024 * CIN;                    // 512*1024 bf16 (vl)

    float* ws     = (float*)d_ws;
    float* maskp  = ws;                      // 16*4096 raw w_qr sums
    float* gmean  = maskp + BATCH * HW;      // 16*512
    float* ctx    = gmean + BATCH * CH;      // 16*512 (unnormalized ctxu)
    float* cattnp = ctx   + BATCH * CH;      // 16*4096
    float* avgx   = cattnp + BATCH * HW;     // 16*512
    float* sattn  = avgx  + BATCH * CH;      // 16*512
    float* sden   = sattn + BATCH * CH;      // 16

    // zero atomic targets: maskp, gmean, ctx, cattnp (contiguous)
    hipMemsetAsync(maskp, 0,
                   (size_t)(BATCH * HW * 2 + BATCH * CH * 2) * sizeof(float), stream);

    // prep: 16384 transpose blocks + 6144 weight-convert blocks
    prep_k<<<22528, 256, 0, stream>>>(x, w_qr, w_vr, w_ql, w_vl, xt, maskp, wA, wB);

    // GEMM-A: MT=4 (ql rows 0-511 -> gmean; vr rows 512-1023 -> ctxu)
    mfma_gemm256<<<1024, 512, 0, stream>>>(
        xt, wA, 4, 0, maskp, nullptr, gmean, ctx, nullptr);
    // channel softmax + spatial softmax denominator (one launch)
    smch_S_k<<<32, 256, 0, stream>>>(gmean, maskp, avgx, sden);
    // GEMM-B: MT=2 (vl rows -> cattnp)
    mfma_gemm256<<<512, 512, 0, stream>>>(
        xt, wB, 2, 1, nullptr, avgx, nullptr, nullptr, cattnp);
    // LN(ctxu/S)+sigmoid and sigmoid(cattnp) (one launch)
    lnsig_k<<<272, 256, 0, stream>>>(ctx, sden, sattn, cattnp);
    final_k<<<dim3(CIN, BATCH), 256, 0, stream>>>(x, sattn, cattnp, out);
}